// Round 5
// baseline (333.346 us; speedup 1.0000x reference)
//
#include <hip/hip_runtime.h>

#define BATCH 4
#define HH 1024
#define WW 1024

// ---------------- fused downsample(1024->256) + conv0 (3->8, s2, relu) -------
__global__ __launch_bounds__(256) void dsconv0_k(const float* __restrict__ img,
                                                 const float* __restrict__ wgt,
                                                 const float* __restrict__ bias,
                                                 float* __restrict__ out) {
  int blk = blockIdx.x;            // b*64 + ty*8 + tx
  int tx = blk & 7;
  int ty = (blk >> 3) & 7;
  int b = blk >> 6;
  int t = threadIdx.x;

  __shared__ float low[3][33][36];  // padded row stride 36

  int Y0 = ty << 4, X0 = tx << 4;  // output tile origin (128x128 space)
  int gy0 = 2 * Y0 - 1, gx0 = 2 * X0 - 1;  // low-res support origin

  for (int i = t; i < 3 * 33 * 33; i += 256) {
    int c = i / 1089;
    int rem = i - c * 1089;
    int ly = rem / 33;
    int lx = rem - ly * 33;
    int gy = gy0 + ly, gx = gx0 + lx;
    float v = 0.f;
    if (gy >= 0 && gx >= 0) {
      const float* p = img + (size_t)(b * 3 + c) * HH * WW + (4 * gy + 1) * WW + 4 * gx + 1;
      v = 0.25f * (p[0] + p[1] + p[WW] + p[WW + 1]);
    }
    low[c][ly][lx] = v;
  }
  __syncthreads();

  int x = t & 15, y = t >> 4;
  float acc[8];
#pragma unroll
  for (int o = 0; o < 8; ++o) acc[o] = bias[o];
  for (int ci = 0; ci < 3; ++ci) {
#pragma unroll
    for (int ky = 0; ky < 3; ++ky) {
#pragma unroll
      for (int kx = 0; kx < 3; ++kx) {
        float v = low[ci][2 * y + ky][2 * x + kx];
#pragma unroll
        for (int o = 0; o < 8; ++o)
          acc[o] += wgt[o * 27 + ci * 9 + ky * 3 + kx] * v;
      }
    }
  }
  float* ob = out + (size_t)b * 8 * 128 * 128 + (Y0 + y) * 128 + X0 + x;
#pragma unroll
  for (int o = 0; o < 8; ++o) ob[o * 128 * 128] = fmaxf(acc[o], 0.f);
}

// ---------------- 3x3 stride-2 conv, pad 1, relu ------------------------------
template <int CI, int CO, int HI>
__global__ __launch_bounds__(256) void conv_s2_k(const float* __restrict__ in,
                                                 const float* __restrict__ wgt,
                                                 const float* __restrict__ bias,
                                                 float* __restrict__ out) {
  const int WI = HI;
  const int HO = HI / 2, WO = HI / 2;
  int idx = blockIdx.x * 256 + threadIdx.x;
  if (idx >= BATCH * CO * HO * WO) return;
  int x = idx % WO;
  int t = idx / WO;
  int y = t % HO; t /= HO;
  int o = t % CO;
  int b = t / CO;
  float acc = bias[o];
  int iy0 = 2 * y - 1, ix0 = 2 * x - 1;
  for (int ci = 0; ci < CI; ++ci) {
    const float* ip = in + (size_t)(b * CI + ci) * HI * WI;
    const float* wp = wgt + (o * CI + ci) * 9;
#pragma unroll
    for (int ky = 0; ky < 3; ++ky) {
      int iy = iy0 + ky;
      if (iy < 0 || iy >= HI) continue;
#pragma unroll
      for (int kx = 0; kx < 3; ++kx) {
        int ix = ix0 + kx;
        if (ix < 0 || ix >= WI) continue;
        acc += wp[ky * 3 + kx] * ip[iy * WI + ix];
      }
    }
  }
  out[idx] = fmaxf(acc, 0.0f);
}

// ---------------- global path from x3: composed splat + cpool + 2 FC ----------
// c = relu(cw . splat) with splat = spw.x3 + (spb+val)  (splat has NO relu, so
// composition eff = cw.spw, ebias = cb + cw.(spb+val) is exact).
__global__ __launch_bounds__(256) void cpfc_k(const float* __restrict__ x3,
                                              const float* __restrict__ spw,
                                              const float* __restrict__ spb,
                                              const float* __restrict__ val,
                                              const float* __restrict__ cw,
                                              const float* __restrict__ cb,
                                              const float* __restrict__ fw1,
                                              const float* __restrict__ fb1,
                                              const float* __restrict__ fw2,
                                              const float* __restrict__ fb2,
                                              float* __restrict__ fc2o) {
  __shared__ float eff[4][64];
  __shared__ float eb[4][4];
  __shared__ float sc[256];
  __shared__ float h1[256];
  int t = threadIdx.x;

  {  // eff[ch][k] = sum_c cw[ch][c] * spw[c][k]
    int ch = t >> 6, k = t & 63;
    float a = 0.f;
#pragma unroll 8
    for (int c = 0; c < 64; ++c) a += cw[ch * 64 + c] * spw[c * 64 + k];
    eff[ch][k] = a;
  }
  if (t < 16) {  // eb[b][ch] = cb[ch] + sum_c cw[ch][c]*(spb[c]+val[b])
    int b = t >> 2, ch = t & 3;
    float a = cb[ch];
    float vb = val[b];
#pragma unroll 8
    for (int c = 0; c < 64; ++c) a += cw[ch * 64 + c] * (spb[c] + vb);
    eb[b][ch] = a;
  }
  __syncthreads();

  int b = t >> 6;
  int r = t & 63;
  int ch = r >> 4;
  int py = (r >> 2) & 3;
  int px = r & 3;
  float sum = 0.f;
  for (int dy = 0; dy < 2; ++dy)
    for (int dx = 0; dx < 2; ++dx) {
      int p = (py * 2 + dy) * 32 + (px * 2 + dx) * 2;  // ::2,::2 of 16x16
      float acc = eb[b][ch];
      const float* xb = x3 + ((size_t)b * 64) * 256 + p;
#pragma unroll 8
      for (int k = 0; k < 64; ++k) acc += eff[ch][k] * xb[k * 256];
      sum += fmaxf(acc, 0.f);
    }
  sc[t] = sum * 0.25f;
  __syncthreads();
  int o = t & 63;
  float acc = fb1[o];
#pragma unroll 8
  for (int k = 0; k < 64; ++k) acc += fw1[o * 64 + k] * sc[b * 64 + k];
  h1[t] = fmaxf(acc, 0.f);
  __syncthreads();
  acc = fb2[o];
#pragma unroll 8
  for (int k = 0; k < 64; ++k) acc += fw2[o * 64 + k] * h1[b * 64 + k];
  fc2o[t] = fmaxf(acc, 0.f);
}

// ---------------- fused pointwise chain: splat->loc1->loc2->loc3->coeff -------
// 32 blocks = 4 batches x 8 pixel-groups (32 px each). Activations ping-pong in
// LDS [128][36] (row stride 36 floats -> 16B-aligned float4 rows). Each thread
// computes a 4px x (CO/32) output tile.
template <int CI, int CO, int RELU>
__device__ __forceinline__ void pw_tile(const float (*__restrict__ X)[36],
                                        float (*__restrict__ Y)[36],
                                        const float* __restrict__ w,
                                        const float* __restrict__ bias,
                                        float badd, int t) {
  constexpr int NO = CO / 32;
  int pg = (t & 7) << 2;
  int og = t >> 3;
  float acc[NO][4];
#pragma unroll
  for (int j = 0; j < NO; ++j) {
    float bb = bias[og * NO + j] + badd;
#pragma unroll
    for (int u = 0; u < 4; ++u) acc[j][u] = bb;
  }
#pragma unroll 4
  for (int k = 0; k < CI; k += 4) {
    float4 xv0 = *(const float4*)&X[k][pg];
    float4 xv1 = *(const float4*)&X[k + 1][pg];
    float4 xv2 = *(const float4*)&X[k + 2][pg];
    float4 xv3 = *(const float4*)&X[k + 3][pg];
#pragma unroll
    for (int j = 0; j < NO; ++j) {
      float4 wv = *(const float4*)&w[(og * NO + j) * CI + k];
      acc[j][0] += wv.x * xv0.x + wv.y * xv1.x + wv.z * xv2.x + wv.w * xv3.x;
      acc[j][1] += wv.x * xv0.y + wv.y * xv1.y + wv.z * xv2.y + wv.w * xv3.y;
      acc[j][2] += wv.x * xv0.z + wv.y * xv1.z + wv.z * xv2.z + wv.w * xv3.z;
      acc[j][3] += wv.x * xv0.w + wv.y * xv1.w + wv.z * xv2.w + wv.w * xv3.w;
    }
  }
#pragma unroll
  for (int j = 0; j < NO; ++j) {
    int o = og * NO + j;
#pragma unroll
    for (int u = 0; u < 4; ++u) {
      float v = acc[j][u];
      if (RELU) v = fmaxf(v, 0.f);
      Y[o][pg + u] = v;
    }
  }
}

__global__ __launch_bounds__(256) void mlp_k(
    const float* __restrict__ x3, const float* __restrict__ spw,
    const float* __restrict__ spb, const float* __restrict__ val,
    const float* __restrict__ lw1, const float* __restrict__ lb1,
    const float* __restrict__ lw2, const float* __restrict__ lb2,
    const float* __restrict__ lw3, const float* __restrict__ lb3,
    const float* __restrict__ fc2o, const float* __restrict__ gw,
    const float* __restrict__ gb, float* __restrict__ gridt) {
  int blk = blockIdx.x;  // b*8 + pg
  int b = blk >> 3;
  int p0 = (blk & 7) << 5;
  int t = threadIdx.x;

  __shared__ float A[128][36];
  __shared__ float Bf[128][36];

  // stage x3 tile: 64 ch x 32 px
  for (int i = t; i < 64 * 32; i += 256) {
    int c = i >> 5, p = i & 31;
    A[c][p] = x3[((size_t)(b * 64 + c)) * 256 + p0 + p];
  }
  __syncthreads();

  pw_tile<64, 64, 0>(A, Bf, spw, spb, val[b], t);   // splat (no relu)
  __syncthreads();
  pw_tile<64, 128, 1>(Bf, A, lw1, lb1, 0.f, t);     // loc1
  __syncthreads();
  pw_tile<128, 128, 1>(A, Bf, lw2, lb2, 0.f, t);    // loc2
  __syncthreads();
  pw_tile<128, 64, 1>(Bf, A, lw3, lb3, 0.f, t);     // loc3
  __syncthreads();

  // coeff: input transform max(loc3 + c_b[k], 0), output 96ch -> gridt scatter
  {
    int pg = (t & 7) << 2;
    int og = t >> 3;  // NO = 3
    float acc[3][4];
#pragma unroll
    for (int j = 0; j < 3; ++j) {
      float bb = gb[og * 3 + j];
#pragma unroll
      for (int u = 0; u < 4; ++u) acc[j][u] = bb;
    }
    const float* cv = fc2o + b * 64;
#pragma unroll 4
    for (int k = 0; k < 64; k += 4) {
      float4 cc4 = *(const float4*)&cv[k];
      float4 xv0 = *(const float4*)&A[k][pg];
      float4 xv1 = *(const float4*)&A[k + 1][pg];
      float4 xv2 = *(const float4*)&A[k + 2][pg];
      float4 xv3 = *(const float4*)&A[k + 3][pg];
      xv0.x = fmaxf(xv0.x + cc4.x, 0.f); xv0.y = fmaxf(xv0.y + cc4.x, 0.f);
      xv0.z = fmaxf(xv0.z + cc4.x, 0.f); xv0.w = fmaxf(xv0.w + cc4.x, 0.f);
      xv1.x = fmaxf(xv1.x + cc4.y, 0.f); xv1.y = fmaxf(xv1.y + cc4.y, 0.f);
      xv1.z = fmaxf(xv1.z + cc4.y, 0.f); xv1.w = fmaxf(xv1.w + cc4.y, 0.f);
      xv2.x = fmaxf(xv2.x + cc4.z, 0.f); xv2.y = fmaxf(xv2.y + cc4.z, 0.f);
      xv2.z = fmaxf(xv2.z + cc4.z, 0.f); xv2.w = fmaxf(xv2.w + cc4.z, 0.f);
      xv3.x = fmaxf(xv3.x + cc4.w, 0.f); xv3.y = fmaxf(xv3.y + cc4.w, 0.f);
      xv3.z = fmaxf(xv3.z + cc4.w, 0.f); xv3.w = fmaxf(xv3.w + cc4.w, 0.f);
#pragma unroll
      for (int j = 0; j < 3; ++j) {
        float4 wv = *(const float4*)&gw[(og * 3 + j) * 64 + k];
        acc[j][0] += wv.x * xv0.x + wv.y * xv1.x + wv.z * xv2.x + wv.w * xv3.x;
        acc[j][1] += wv.x * xv0.y + wv.y * xv1.y + wv.z * xv2.y + wv.w * xv3.y;
        acc[j][2] += wv.x * xv0.z + wv.y * xv1.z + wv.z * xv2.z + wv.w * xv3.z;
        acc[j][3] += wv.x * xv0.w + wv.y * xv1.w + wv.z * xv2.w + wv.w * xv3.w;
      }
    }
#pragma unroll
    for (int j = 0; j < 3; ++j) {
      int o = og * 3 + j;
      int l = o / 12, cc = o - l * 12;
#pragma unroll
      for (int u = 0; u < 4; ++u)
        gridt[(size_t)(((b * 8 + l) << 8) + p0 + pg + u) * 12 + cc] = acc[j][u];
    }
  }
}

// ---------------- guide + bilateral slice + affine apply (fused, LDS grid) ----
#define ZST 200
__global__ __launch_bounds__(256) void slice_k(
    const float* __restrict__ img, const float* __restrict__ gridt,
    const float* __restrict__ ccm_w, const float* __restrict__ ccm_b,
    const float* __restrict__ shifts, const float* __restrict__ slopes,
    const float* __restrict__ prw, const float* __restrict__ prb,
    float* __restrict__ out) {
  int blk = blockIdx.x;          // BATCH*1024
  int b = blk >> 10;
  int h = blk & 1023;
  int t = threadIdx.x;

  __shared__ float sg[8 * ZST];  // 6400 B

  float cy = (h + 0.5f) * 0.015625f - 0.5f;
  float y0f = floorf(cy);
  float wy = cy - y0f;
  int y0 = (int)y0f;
  int yi0 = min(max(y0, 0), 15), yi1 = min(max(y0 + 1, 0), 15);

  // stage y-lerped grid: 8 slabs x 48 float4
  for (int i = t; i < 384; i += 256) {
    int z = i / 48;
    int e = i - z * 48;
    const float4* s0 =
        (const float4*)(gridt + (size_t)(((b * 8 + z) << 8) + (yi0 << 4)) * 12);
    const float4* s1 =
        (const float4*)(gridt + (size_t)(((b * 8 + z) << 8) + (yi1 << 4)) * 12);
    float4 a = s0[e], c = s1[e];
    float4 v = make_float4(a.x + wy * (c.x - a.x), a.y + wy * (c.y - a.y),
                           a.z + wy * (c.z - a.z), a.w + wy * (c.w - a.w));
    *((float4*)(sg + z * ZST) + e) = v;
  }
  __syncthreads();

  int pp = (h << 10) + (t << 2);
  const float* ib = img + (size_t)b * 3 * HH * WW;
  float4 R4 = *(const float4*)(ib + pp);
  float4 G4 = *(const float4*)(ib + HH * WW + pp);
  float4 B4 = *(const float4*)(ib + 2 * HH * WW + pp);
  float r_[4] = {R4.x, R4.y, R4.z, R4.w};
  float g_[4] = {G4.x, G4.y, G4.z, G4.w};
  float b_[4] = {B4.x, B4.y, B4.z, B4.w};

  float m0 = ccm_w[0], m1 = ccm_w[1], m2 = ccm_w[2];
  float m3 = ccm_w[3], m4 = ccm_w[4], m5 = ccm_w[5];
  float m6 = ccm_w[6], m7 = ccm_w[7], m8 = ccm_w[8];
  float c0 = ccm_b[0], c1 = ccm_b[1], c2 = ccm_b[2];
  float p0 = prw[0], p1 = prw[1], p2 = prw[2], pb = prb[0];

  float ro[4], go[4], bo[4];
#pragma unroll
  for (int j = 0; j < 4; ++j) {
    float r = r_[j], g = g_[j], bl = b_[j];
    float v0 = c0 + m0 * r + m1 * g + m2 * bl;
    float v1 = c1 + m3 * r + m4 * g + m5 * bl;
    float v2 = c2 + m6 * r + m7 * g + m8 * bl;
    float t0 = 0.f, t1 = 0.f, t2 = 0.f;
#pragma unroll
    for (int k = 0; k < 16; ++k) {
      t0 += slopes[k] * fmaxf(v0 - shifts[k], 0.f);
      t1 += slopes[16 + k] * fmaxf(v1 - shifts[16 + k], 0.f);
      t2 += slopes[32 + k] * fmaxf(v2 - shifts[32 + k], 0.f);
    }
    float gg = pb + p0 * t0 + p1 * t1 + p2 * t2;
    float guide = fminf(fmaxf(gg, 0.f), 1.f);

    int w = (t << 2) + j;
    float cx = (w + 0.5f) * 0.015625f - 0.5f;
    float x0f = floorf(cx);
    float wx = cx - x0f;
    int x0i = (int)x0f;
    int xi0 = min(max(x0i, 0), 15), xi1 = min(max(x0i + 1, 0), 15);

    float cz = guide * 8.0f - 0.5f;
    float z0f = floorf(cz);
    float wz = cz - z0f;
    int z0i = (int)z0f;
    int zi0 = min(max(z0i, 0), 7), zi1 = min(max(z0i + 1, 0), 7);

    int oz0 = zi0 * ZST, oz1 = zi1 * ZST;
    int ox0 = xi0 * 12, ox1 = xi1 * 12;
    float wz1 = wz, wz0 = 1.f - wz;
    float wx1 = wx, wx0 = 1.f - wx;

    float acc[12];
#pragma unroll
    for (int k = 0; k < 12; ++k) acc[k] = 0.f;

#pragma unroll
    for (int dz = 0; dz < 2; ++dz) {
      int oz = dz ? oz1 : oz0;
      float wzz = dz ? wz1 : wz0;
#pragma unroll
      for (int dx = 0; dx < 2; ++dx) {
        int ox = dx ? ox1 : ox0;
        float wgt = wzz * (dx ? wx1 : wx0);
        const float* gp = sg + oz + ox;
        float4 a0 = *(const float4*)gp;
        float4 a1 = *(const float4*)(gp + 4);
        float4 a2 = *(const float4*)(gp + 8);
        acc[0] += wgt * a0.x;  acc[1] += wgt * a0.y;
        acc[2] += wgt * a0.z;  acc[3] += wgt * a0.w;
        acc[4] += wgt * a1.x;  acc[5] += wgt * a1.y;
        acc[6] += wgt * a1.z;  acc[7] += wgt * a1.w;
        acc[8] += wgt * a2.x;  acc[9] += wgt * a2.y;
        acc[10] += wgt * a2.z; acc[11] += wgt * a2.w;
      }
    }
    ro[j] = acc[0] * r + acc[1] * g + acc[2] * bl + acc[3];
    go[j] = acc[4] * r + acc[5] * g + acc[6] * bl + acc[7];
    bo[j] = acc[8] * r + acc[9] * g + acc[10] * bl + acc[11];
  }
  float* ob = out + (size_t)b * 3 * HH * WW;
  *(float4*)(ob + pp) = make_float4(ro[0], ro[1], ro[2], ro[3]);
  *(float4*)(ob + HH * WW + pp) = make_float4(go[0], go[1], go[2], go[3]);
  *(float4*)(ob + 2 * HH * WW + pp) = make_float4(bo[0], bo[1], bo[2], bo[3]);
}

extern "C" void kernel_launch(void* const* d_in, const int* in_sizes, int n_in,
                              void* d_out, int out_size, void* d_ws, size_t ws_size,
                              hipStream_t stream) {
  const float* image = (const float*)d_in[0];
  const float* val   = (const float*)d_in[1];
  const float* sw0 = (const float*)d_in[2];  const float* sb0 = (const float*)d_in[3];
  const float* sw1 = (const float*)d_in[4];  const float* sb1 = (const float*)d_in[5];
  const float* sw2 = (const float*)d_in[6];  const float* sb2 = (const float*)d_in[7];
  const float* sw3 = (const float*)d_in[8];  const float* sb3 = (const float*)d_in[9];
  const float* spw = (const float*)d_in[10]; const float* spb = (const float*)d_in[11];
  const float* lw1 = (const float*)d_in[12]; const float* lb1 = (const float*)d_in[13];
  const float* lw2 = (const float*)d_in[14]; const float* lb2 = (const float*)d_in[15];
  const float* lw3 = (const float*)d_in[16]; const float* lb3 = (const float*)d_in[17];
  const float* cw  = (const float*)d_in[18]; const float* cb  = (const float*)d_in[19];
  const float* fw1 = (const float*)d_in[20]; const float* fb1 = (const float*)d_in[21];
  const float* fw2 = (const float*)d_in[22]; const float* fb2 = (const float*)d_in[23];
  const float* gw  = (const float*)d_in[24]; const float* gb  = (const float*)d_in[25];
  const float* ccm_w = (const float*)d_in[26]; const float* ccm_b = (const float*)d_in[27];
  const float* shifts = (const float*)d_in[28]; const float* slopes = (const float*)d_in[29];
  const float* prw = (const float*)d_in[30]; const float* prb = (const float*)d_in[31];
  float* out = (float*)d_out;

  float* ws    = (float*)d_ws;
  float* x0    = ws;                  // 524288
  float* x1    = x0 + 524288;         // 262144
  float* x2    = x1 + 262144;         // 131072
  float* x3    = x2 + 131072;         // 65536
  float* fc2o  = x3 + 65536;          // 256
  float* gridt = fc2o + 256;          // 98304

  dsconv0_k<<<256, 256, 0, stream>>>(image, sw0, sb0, x0);
  conv_s2_k<8, 16, 128><<<1024, 256, 0, stream>>>(x0, sw1, sb1, x1);
  conv_s2_k<16, 32, 64><<<512, 256, 0, stream>>>(x1, sw2, sb2, x2);
  conv_s2_k<32, 64, 32><<<256, 256, 0, stream>>>(x2, sw3, sb3, x3);
  cpfc_k<<<1, 256, 0, stream>>>(x3, spw, spb, val, cw, cb, fw1, fb1, fw2, fb2,
                                fc2o);
  mlp_k<<<32, 256, 0, stream>>>(x3, spw, spb, val, lw1, lb1, lw2, lb2, lw3, lb3,
                                fc2o, gw, gb, gridt);
  slice_k<<<4096, 256, 0, stream>>>(image, gridt, ccm_w, ccm_b, shifts, slopes,
                                    prw, prb, out);
}

// Round 6
// 327.460 us; speedup vs baseline: 1.0180x; 1.0180x over previous
//
#include <hip/hip_runtime.h>

#define BATCH 4
#define HH 1024
#define WW 1024

// ---------------- fused downsample(1024->256) + conv0 (3->8, s2, relu) -------
__global__ __launch_bounds__(256) void dsconv0_k(const float* __restrict__ img,
                                                 const float* __restrict__ wgt,
                                                 const float* __restrict__ bias,
                                                 float* __restrict__ out) {
  int blk = blockIdx.x;            // b*64 + ty*8 + tx
  int tx = blk & 7;
  int ty = (blk >> 3) & 7;
  int b = blk >> 6;
  int t = threadIdx.x;

  __shared__ float low[3][33][36];  // padded row stride 36

  int Y0 = ty << 4, X0 = tx << 4;  // output tile origin (128x128 space)
  int gy0 = 2 * Y0 - 1, gx0 = 2 * X0 - 1;  // low-res support origin

  for (int i = t; i < 3 * 33 * 33; i += 256) {
    int c = i / 1089;
    int rem = i - c * 1089;
    int ly = rem / 33;
    int lx = rem - ly * 33;
    int gy = gy0 + ly, gx = gx0 + lx;
    float v = 0.f;
    if (gy >= 0 && gx >= 0) {
      const float* p = img + (size_t)(b * 3 + c) * HH * WW + (4 * gy + 1) * WW + 4 * gx + 1;
      v = 0.25f * (p[0] + p[1] + p[WW] + p[WW + 1]);
    }
    low[c][ly][lx] = v;
  }
  __syncthreads();

  int x = t & 15, y = t >> 4;
  float acc[8];
#pragma unroll
  for (int o = 0; o < 8; ++o) acc[o] = bias[o];
  for (int ci = 0; ci < 3; ++ci) {
#pragma unroll
    for (int ky = 0; ky < 3; ++ky) {
#pragma unroll
      for (int kx = 0; kx < 3; ++kx) {
        float v = low[ci][2 * y + ky][2 * x + kx];
#pragma unroll
        for (int o = 0; o < 8; ++o)
          acc[o] += wgt[o * 27 + ci * 9 + ky * 3 + kx] * v;
      }
    }
  }
  float* ob = out + (size_t)b * 8 * 128 * 128 + (Y0 + y) * 128 + X0 + x;
#pragma unroll
  for (int o = 0; o < 8; ++o) ob[o * 128 * 128] = fmaxf(acc[o], 0.f);
}

// ---------------- 3x3 stride-2 conv, pad 1, relu ------------------------------
template <int CI, int CO, int HI>
__global__ __launch_bounds__(256) void conv_s2_k(const float* __restrict__ in,
                                                 const float* __restrict__ wgt,
                                                 const float* __restrict__ bias,
                                                 float* __restrict__ out) {
  const int WI = HI;
  const int HO = HI / 2, WO = HI / 2;
  int idx = blockIdx.x * 256 + threadIdx.x;
  if (idx >= BATCH * CO * HO * WO) return;
  int x = idx % WO;
  int t = idx / WO;
  int y = t % HO; t /= HO;
  int o = t % CO;
  int b = t / CO;
  float acc = bias[o];
  int iy0 = 2 * y - 1, ix0 = 2 * x - 1;
  for (int ci = 0; ci < CI; ++ci) {
    const float* ip = in + (size_t)(b * CI + ci) * HI * WI;
    const float* wp = wgt + (o * CI + ci) * 9;
#pragma unroll
    for (int ky = 0; ky < 3; ++ky) {
      int iy = iy0 + ky;
      if (iy < 0 || iy >= HI) continue;
#pragma unroll
      for (int kx = 0; kx < 3; ++kx) {
        int ix = ix0 + kx;
        if (ix < 0 || ix >= WI) continue;
        acc += wp[ky * 3 + kx] * ip[iy * WI + ix];
      }
    }
  }
  out[idx] = fmaxf(acc, 0.0f);
}

// ---------------- global path from x3: composed splat + cpool + 2 FC ----------
__global__ __launch_bounds__(256) void cpfc_k(const float* __restrict__ x3,
                                              const float* __restrict__ spw,
                                              const float* __restrict__ spb,
                                              const float* __restrict__ val,
                                              const float* __restrict__ cw,
                                              const float* __restrict__ cb,
                                              const float* __restrict__ fw1,
                                              const float* __restrict__ fb1,
                                              const float* __restrict__ fw2,
                                              const float* __restrict__ fb2,
                                              float* __restrict__ fc2o) {
  __shared__ float eff[4][64];
  __shared__ float eb[4][4];
  __shared__ float sc[256];
  __shared__ float h1[256];
  int t = threadIdx.x;

  {  // eff[ch][k] = sum_c cw[ch][c] * spw[c][k]
    int ch = t >> 6, k = t & 63;
    float a = 0.f;
#pragma unroll 8
    for (int c = 0; c < 64; ++c) a += cw[ch * 64 + c] * spw[c * 64 + k];
    eff[ch][k] = a;
  }
  if (t < 16) {  // eb[b][ch] = cb[ch] + sum_c cw[ch][c]*(spb[c]+val[b])
    int b = t >> 2, ch = t & 3;
    float a = cb[ch];
    float vb = val[b];
#pragma unroll 8
    for (int c = 0; c < 64; ++c) a += cw[ch * 64 + c] * (spb[c] + vb);
    eb[b][ch] = a;
  }
  __syncthreads();

  int b = t >> 6;
  int r = t & 63;
  int ch = r >> 4;
  int py = (r >> 2) & 3;
  int px = r & 3;
  float sum = 0.f;
  for (int dy = 0; dy < 2; ++dy)
    for (int dx = 0; dx < 2; ++dx) {
      int p = (py * 2 + dy) * 32 + (px * 2 + dx) * 2;  // ::2,::2 of 16x16
      float acc = eb[b][ch];
      const float* xb = x3 + ((size_t)b * 64) * 256 + p;
#pragma unroll 8
      for (int k = 0; k < 64; ++k) acc += eff[ch][k] * xb[k * 256];
      sum += fmaxf(acc, 0.f);
    }
  sc[t] = sum * 0.25f;
  __syncthreads();
  int o = t & 63;
  float acc = fb1[o];
#pragma unroll 8
  for (int k = 0; k < 64; ++k) acc += fw1[o * 64 + k] * sc[b * 64 + k];
  h1[t] = fmaxf(acc, 0.f);
  __syncthreads();
  acc = fb2[o];
#pragma unroll 8
  for (int k = 0; k < 64; ++k) acc += fw2[o * 64 + k] * h1[b * 64 + k];
  fc2o[t] = fmaxf(acc, 0.f);
}

// ---------------- fused pointwise chain: splat->loc1->loc2->loc3->coeff -------
template <int CI, int CO, int RELU>
__device__ __forceinline__ void pw_tile(const float (*__restrict__ X)[36],
                                        float (*__restrict__ Y)[36],
                                        const float* __restrict__ w,
                                        const float* __restrict__ bias,
                                        float badd, int t) {
  constexpr int NO = CO / 32;
  int pg = (t & 7) << 2;
  int og = t >> 3;
  float acc[NO][4];
#pragma unroll
  for (int j = 0; j < NO; ++j) {
    float bb = bias[og * NO + j] + badd;
#pragma unroll
    for (int u = 0; u < 4; ++u) acc[j][u] = bb;
  }
#pragma unroll 4
  for (int k = 0; k < CI; k += 4) {
    float4 xv0 = *(const float4*)&X[k][pg];
    float4 xv1 = *(const float4*)&X[k + 1][pg];
    float4 xv2 = *(const float4*)&X[k + 2][pg];
    float4 xv3 = *(const float4*)&X[k + 3][pg];
#pragma unroll
    for (int j = 0; j < NO; ++j) {
      float4 wv = *(const float4*)&w[(og * NO + j) * CI + k];
      acc[j][0] += wv.x * xv0.x + wv.y * xv1.x + wv.z * xv2.x + wv.w * xv3.x;
      acc[j][1] += wv.x * xv0.y + wv.y * xv1.y + wv.z * xv2.y + wv.w * xv3.y;
      acc[j][2] += wv.x * xv0.z + wv.y * xv1.z + wv.z * xv2.z + wv.w * xv3.z;
      acc[j][3] += wv.x * xv0.w + wv.y * xv1.w + wv.z * xv2.w + wv.w * xv3.w;
    }
  }
#pragma unroll
  for (int j = 0; j < NO; ++j) {
    int o = og * NO + j;
#pragma unroll
    for (int u = 0; u < 4; ++u) {
      float v = acc[j][u];
      if (RELU) v = fmaxf(v, 0.f);
      Y[o][pg + u] = v;
    }
  }
}

__global__ __launch_bounds__(256) void mlp_k(
    const float* __restrict__ x3, const float* __restrict__ spw,
    const float* __restrict__ spb, const float* __restrict__ val,
    const float* __restrict__ lw1, const float* __restrict__ lb1,
    const float* __restrict__ lw2, const float* __restrict__ lb2,
    const float* __restrict__ lw3, const float* __restrict__ lb3,
    const float* __restrict__ fc2o, const float* __restrict__ gw,
    const float* __restrict__ gb, float* __restrict__ gridt) {
  int blk = blockIdx.x;  // b*8 + pg
  int b = blk >> 3;
  int p0 = (blk & 7) << 5;
  int t = threadIdx.x;

  __shared__ float A[128][36];
  __shared__ float Bf[128][36];

  for (int i = t; i < 64 * 32; i += 256) {
    int c = i >> 5, p = i & 31;
    A[c][p] = x3[((size_t)(b * 64 + c)) * 256 + p0 + p];
  }
  __syncthreads();

  pw_tile<64, 64, 0>(A, Bf, spw, spb, val[b], t);   // splat (no relu)
  __syncthreads();
  pw_tile<64, 128, 1>(Bf, A, lw1, lb1, 0.f, t);     // loc1
  __syncthreads();
  pw_tile<128, 128, 1>(A, Bf, lw2, lb2, 0.f, t);    // loc2
  __syncthreads();
  pw_tile<128, 64, 1>(Bf, A, lw3, lb3, 0.f, t);     // loc3
  __syncthreads();

  {
    int pg = (t & 7) << 2;
    int og = t >> 3;  // NO = 3
    float acc[3][4];
#pragma unroll
    for (int j = 0; j < 3; ++j) {
      float bb = gb[og * 3 + j];
#pragma unroll
      for (int u = 0; u < 4; ++u) acc[j][u] = bb;
    }
    const float* cv = fc2o + b * 64;
#pragma unroll 4
    for (int k = 0; k < 64; k += 4) {
      float4 cc4 = *(const float4*)&cv[k];
      float4 xv0 = *(const float4*)&A[k][pg];
      float4 xv1 = *(const float4*)&A[k + 1][pg];
      float4 xv2 = *(const float4*)&A[k + 2][pg];
      float4 xv3 = *(const float4*)&A[k + 3][pg];
      xv0.x = fmaxf(xv0.x + cc4.x, 0.f); xv0.y = fmaxf(xv0.y + cc4.x, 0.f);
      xv0.z = fmaxf(xv0.z + cc4.x, 0.f); xv0.w = fmaxf(xv0.w + cc4.x, 0.f);
      xv1.x = fmaxf(xv1.x + cc4.y, 0.f); xv1.y = fmaxf(xv1.y + cc4.y, 0.f);
      xv1.z = fmaxf(xv1.z + cc4.y, 0.f); xv1.w = fmaxf(xv1.w + cc4.y, 0.f);
      xv2.x = fmaxf(xv2.x + cc4.z, 0.f); xv2.y = fmaxf(xv2.y + cc4.z, 0.f);
      xv2.z = fmaxf(xv2.z + cc4.z, 0.f); xv2.w = fmaxf(xv2.w + cc4.z, 0.f);
      xv3.x = fmaxf(xv3.x + cc4.w, 0.f); xv3.y = fmaxf(xv3.y + cc4.w, 0.f);
      xv3.z = fmaxf(xv3.z + cc4.w, 0.f); xv3.w = fmaxf(xv3.w + cc4.w, 0.f);
#pragma unroll
      for (int j = 0; j < 3; ++j) {
        float4 wv = *(const float4*)&gw[(og * 3 + j) * 64 + k];
        acc[j][0] += wv.x * xv0.x + wv.y * xv1.x + wv.z * xv2.x + wv.w * xv3.x;
        acc[j][1] += wv.x * xv0.y + wv.y * xv1.y + wv.z * xv2.y + wv.w * xv3.y;
        acc[j][2] += wv.x * xv0.z + wv.y * xv1.z + wv.z * xv2.z + wv.w * xv3.z;
        acc[j][3] += wv.x * xv0.w + wv.y * xv1.w + wv.z * xv2.w + wv.w * xv3.w;
      }
    }
#pragma unroll
    for (int j = 0; j < 3; ++j) {
      int o = og * 3 + j;
      int l = o / 12, cc = o - l * 12;
#pragma unroll
      for (int u = 0; u < 4; ++u)
        gridt[(size_t)(((b * 8 + l) << 8) + p0 + pg + u) * 12 + cc] = acc[j][u];
    }
  }
}

// ---------------- guide + bilateral slice + affine apply (fused, LDS grid) ----
// Curve LUT: f_c(v) = sum_k slopes[c,k]*relu(v - shifts[c,k]) is piecewise-
// linear on a uniform knot grid (linspace). With CS = cumsum(slopes),
// CB = cumsum(slopes*shifts): f_c(v) = CS[j]*t - CB[j], t = max(v, base_c),
// j = min((t-base_c)*inv_step_c, 15). Continuity makes boundary fp wobble
// harmless. 6 VALU + 1 ds_read_b64 per channel instead of 48 VALU.
#define ZST 200
__global__ __launch_bounds__(256) void slice_k(
    const float* __restrict__ img, const float* __restrict__ gridt,
    const float* __restrict__ ccm_w, const float* __restrict__ ccm_b,
    const float* __restrict__ shifts, const float* __restrict__ slopes,
    const float* __restrict__ prw, const float* __restrict__ prb,
    float* __restrict__ out) {
  int blk = blockIdx.x;          // BATCH*1024
  int b = blk >> 10;
  int h = blk & 1023;
  int t = threadIdx.x;

  __shared__ float sg[8 * ZST];      // 6400 B
  __shared__ float2 lut[3][16];      // CS, CB

  float cy = (h + 0.5f) * 0.015625f - 0.5f;
  float y0f = floorf(cy);
  float wy = cy - y0f;
  int y0 = (int)y0f;
  int yi0 = min(max(y0, 0), 15), yi1 = min(max(y0 + 1, 0), 15);

  if (t < 48) {  // build curve LUT (prefix sums over 16 knots)
    int c = t >> 4, k = t & 15;
    float cs = 0.f, cbv = 0.f;
    for (int i = 0; i <= k; ++i) {
      float s = slopes[c * 16 + i];
      cs += s;
      cbv += s * shifts[c * 16 + i];
    }
    lut[c][k] = make_float2(cs, cbv);
  }

  // stage y-lerped grid: 8 slabs x 48 float4
  for (int i = t; i < 384; i += 256) {
    int z = i / 48;
    int e = i - z * 48;
    const float4* s0 =
        (const float4*)(gridt + (size_t)(((b * 8 + z) << 8) + (yi0 << 4)) * 12);
    const float4* s1 =
        (const float4*)(gridt + (size_t)(((b * 8 + z) << 8) + (yi1 << 4)) * 12);
    float4 a = s0[e], c = s1[e];
    float4 v = make_float4(a.x + wy * (c.x - a.x), a.y + wy * (c.y - a.y),
                           a.z + wy * (c.z - a.z), a.w + wy * (c.w - a.w));
    *((float4*)(sg + z * ZST) + e) = v;
  }
  __syncthreads();

  int pp = (h << 10) + (t << 2);
  const float* ib = img + (size_t)b * 3 * HH * WW;
  float4 R4 = *(const float4*)(ib + pp);
  float4 G4 = *(const float4*)(ib + HH * WW + pp);
  float4 B4 = *(const float4*)(ib + 2 * HH * WW + pp);
  float r_[4] = {R4.x, R4.y, R4.z, R4.w};
  float g_[4] = {G4.x, G4.y, G4.z, G4.w};
  float b_[4] = {B4.x, B4.y, B4.z, B4.w};

  float m0 = ccm_w[0], m1 = ccm_w[1], m2 = ccm_w[2];
  float m3 = ccm_w[3], m4 = ccm_w[4], m5 = ccm_w[5];
  float m6 = ccm_w[6], m7 = ccm_w[7], m8 = ccm_w[8];
  float c0 = ccm_b[0], c1 = ccm_b[1], c2 = ccm_b[2];
  float p0 = prw[0], p1 = prw[1], p2 = prw[2], pb = prb[0];

  float base0 = shifts[0], base1 = shifts[16], base2 = shifts[32];
  float inv0 = 1.0f / (shifts[1] - base0);
  float inv1 = 1.0f / (shifts[17] - base1);
  float inv2 = 1.0f / (shifts[33] - base2);

  float ro[4], go[4], bo[4];
#pragma unroll
  for (int j = 0; j < 4; ++j) {
    float r = r_[j], g = g_[j], bl = b_[j];
    float v0 = c0 + m0 * r + m1 * g + m2 * bl;
    float v1 = c1 + m3 * r + m4 * g + m5 * bl;
    float v2 = c2 + m6 * r + m7 * g + m8 * bl;

    float tv0 = fmaxf(v0, base0);
    float tv1 = fmaxf(v1, base1);
    float tv2 = fmaxf(v2, base2);
    int j0 = min((int)((tv0 - base0) * inv0), 15);
    int j1 = min((int)((tv1 - base1) * inv1), 15);
    int j2 = min((int)((tv2 - base2) * inv2), 15);
    float2 e0 = lut[0][j0];
    float2 e1 = lut[1][j1];
    float2 e2 = lut[2][j2];
    float f0 = e0.x * tv0 - e0.y;
    float f1 = e1.x * tv1 - e1.y;
    float f2 = e2.x * tv2 - e2.y;

    float gg = pb + p0 * f0 + p1 * f1 + p2 * f2;
    float guide = fminf(fmaxf(gg, 0.f), 1.f);

    int w = (t << 2) + j;
    float cx = (w + 0.5f) * 0.015625f - 0.5f;
    float x0f = floorf(cx);
    float wx = cx - x0f;
    int x0i = (int)x0f;
    int xi0 = min(max(x0i, 0), 15), xi1 = min(max(x0i + 1, 0), 15);

    float cz = guide * 8.0f - 0.5f;
    float z0f = floorf(cz);
    float wz = cz - z0f;
    int z0i = (int)z0f;
    int zi0 = min(max(z0i, 0), 7), zi1 = min(max(z0i + 1, 0), 7);

    int oz0 = zi0 * ZST, oz1 = zi1 * ZST;
    int ox0 = xi0 * 12, ox1 = xi1 * 12;
    float wz1 = wz, wz0 = 1.f - wz;
    float wx1 = wx, wx0 = 1.f - wx;

    float acc[12];
#pragma unroll
    for (int k = 0; k < 12; ++k) acc[k] = 0.f;

#pragma unroll
    for (int dz = 0; dz < 2; ++dz) {
      int oz = dz ? oz1 : oz0;
      float wzz = dz ? wz1 : wz0;
#pragma unroll
      for (int dx = 0; dx < 2; ++dx) {
        int ox = dx ? ox1 : ox0;
        float wgt = wzz * (dx ? wx1 : wx0);
        const float* gp = sg + oz + ox;
        float4 a0 = *(const float4*)gp;
        float4 a1 = *(const float4*)(gp + 4);
        float4 a2 = *(const float4*)(gp + 8);
        acc[0] += wgt * a0.x;  acc[1] += wgt * a0.y;
        acc[2] += wgt * a0.z;  acc[3] += wgt * a0.w;
        acc[4] += wgt * a1.x;  acc[5] += wgt * a1.y;
        acc[6] += wgt * a1.z;  acc[7] += wgt * a1.w;
        acc[8] += wgt * a2.x;  acc[9] += wgt * a2.y;
        acc[10] += wgt * a2.z; acc[11] += wgt * a2.w;
      }
    }
    ro[j] = acc[0] * r + acc[1] * g + acc[2] * bl + acc[3];
    go[j] = acc[4] * r + acc[5] * g + acc[6] * bl + acc[7];
    bo[j] = acc[8] * r + acc[9] * g + acc[10] * bl + acc[11];
  }
  float* ob = out + (size_t)b * 3 * HH * WW;
  *(float4*)(ob + pp) = make_float4(ro[0], ro[1], ro[2], ro[3]);
  *(float4*)(ob + HH * WW + pp) = make_float4(go[0], go[1], go[2], go[3]);
  *(float4*)(ob + 2 * HH * WW + pp) = make_float4(bo[0], bo[1], bo[2], bo[3]);
}

extern "C" void kernel_launch(void* const* d_in, const int* in_sizes, int n_in,
                              void* d_out, int out_size, void* d_ws, size_t ws_size,
                              hipStream_t stream) {
  const float* image = (const float*)d_in[0];
  const float* val   = (const float*)d_in[1];
  const float* sw0 = (const float*)d_in[2];  const float* sb0 = (const float*)d_in[3];
  const float* sw1 = (const float*)d_in[4];  const float* sb1 = (const float*)d_in[5];
  const float* sw2 = (const float*)d_in[6];  const float* sb2 = (const float*)d_in[7];
  const float* sw3 = (const float*)d_in[8];  const float* sb3 = (const float*)d_in[9];
  const float* spw = (const float*)d_in[10]; const float* spb = (const float*)d_in[11];
  const float* lw1 = (const float*)d_in[12]; const float* lb1 = (const float*)d_in[13];
  const float* lw2 = (const float*)d_in[14]; const float* lb2 = (const float*)d_in[15];
  const float* lw3 = (const float*)d_in[16]; const float* lb3 = (const float*)d_in[17];
  const float* cw  = (const float*)d_in[18]; const float* cb  = (const float*)d_in[19];
  const float* fw1 = (const float*)d_in[20]; const float* fb1 = (const float*)d_in[21];
  const float* fw2 = (const float*)d_in[22]; const float* fb2 = (const float*)d_in[23];
  const float* gw  = (const float*)d_in[24]; const float* gb  = (const float*)d_in[25];
  const float* ccm_w = (const float*)d_in[26]; const float* ccm_b = (const float*)d_in[27];
  const float* shifts = (const float*)d_in[28]; const float* slopes = (const float*)d_in[29];
  const float* prw = (const float*)d_in[30]; const float* prb = (const float*)d_in[31];
  float* out = (float*)d_out;

  float* ws    = (float*)d_ws;
  float* x0    = ws;                  // 524288
  float* x1    = x0 + 524288;         // 262144
  float* x2    = x1 + 262144;         // 131072
  float* x3    = x2 + 131072;         // 65536
  float* fc2o  = x3 + 65536;          // 256
  float* gridt = fc2o + 256;          // 98304

  dsconv0_k<<<256, 256, 0, stream>>>(image, sw0, sb0, x0);
  conv_s2_k<8, 16, 128><<<1024, 256, 0, stream>>>(x0, sw1, sb1, x1);
  conv_s2_k<16, 32, 64><<<512, 256, 0, stream>>>(x1, sw2, sb2, x2);
  conv_s2_k<32, 64, 32><<<256, 256, 0, stream>>>(x2, sw3, sb3, x3);
  cpfc_k<<<1, 256, 0, stream>>>(x3, spw, spb, val, cw, cb, fw1, fb1, fw2, fb2,
                                fc2o);
  mlp_k<<<32, 256, 0, stream>>>(x3, spw, spb, val, lw1, lb1, lw2, lb2, lw3, lb3,
                                fc2o, gw, gb, gridt);
  slice_k<<<4096, 256, 0, stream>>>(image, gridt, ccm_w, ccm_b, shifts, slopes,
                                    prw, prb, out);
}